// Round 15
// baseline (208.664 us; speedup 1.0000x reference)
//
#include <hip/hip_runtime.h>
#include <math.h>

#define Bb 4
#define Nn 384
#define CSs 384
#define Hh 12
#define Cc 16
#define PQq 4
#define PVv 8
#define FPROJ 1152
#define FCAT 576
#define INFV 100000.0f
#define EPSV 1e-8f

// ws layout (float slots)
#define WS_PROJ 0
#define WS_CAT  3022848      // bf16 cat: 1536*576 shorts
#define WS_PART 4423680      // 48*36 partials, stride 1408 (O bf16 [64][40] | m[64]@1280 | s[64]@1344)
#define PSTRIDE 1408
#define WS_CNT  9068544      // 288 ints (zeroed each call via hipMemsetAsync)
#define WS_AH   9400320
#define WS_AL   9695232
#define WS_KH   9990144
#define WS_KL   10285056
#define WS_VBP  10579968     // 48*384*40 shorts

typedef __attribute__((ext_vector_type(8))) short short8v;
typedef __attribute__((ext_vector_type(4))) float f32x4;

__device__ __forceinline__ short f2bf(float x) {
    unsigned u = __float_as_uint(x);
    unsigned r = (u + 0x7FFFu + ((u >> 16) & 1u)) >> 16;
    return (short)r;
}
__device__ __forceinline__ float bf2f(short h) {
    return __uint_as_float(((unsigned)(unsigned short)h) << 16);
}

__device__ __forceinline__ float get_bias(int f,
    const float* __restrict__ b_q, const float* __restrict__ b_kv,
    const float* __restrict__ b_qp, const float* __restrict__ b_kvp)
{
    if (f < 192) return b_q[f];
    if (f < 576) return b_kv[f - 192];
    if (f < 720) return b_qp[f - 576];
    return b_kvp[f - 720];
}

// ---------------- Kernel 1: projection GEMM via bf16 MFMA (in-kernel conversions) ----------------
// grid 432 = 24 bm x 18 bn; 256 thr. A: s f32->bf16 in staging. B: w f32->bf16 in staging
// (lane=f coalesced reads; per-thread 8-k column -> one short8 LDS write).
__global__ __launch_bounds__(256) void proj_kernel(
    const float* __restrict__ s,
    const float* __restrict__ w_q, const float* __restrict__ w_kv,
    const float* __restrict__ w_qp, const float* __restrict__ w_kvp,
    const float* __restrict__ b_q, const float* __restrict__ b_kv,
    const float* __restrict__ b_qp, const float* __restrict__ b_kvp,
    float* __restrict__ proj)
{
    __shared__ short Al[64 * 40];
    __shared__ short Bl[64 * 40];

    const int bm = blockIdx.x % 24;
    const int bn = blockIdx.x / 24;
    const int m0 = bm * 64;
    const int f0 = bn * 64;
    const int t = threadIdx.x;
    const int w = t >> 6;
    const int lane = t & 63;
    const int lrow = lane & 15;
    const int lkg  = lane >> 4;

    const int srow = t >> 2;         // A staging: 0..63
    const int sseg = t & 3;
    const int fl   = t & 63;         // B staging: f lane
    const int kk8  = t >> 6;         // 0..3 (8 k each)

    // B source select (per thread, f = f0 + fl; boundaries 192/576/720 all 8-aligned,
    // and fl spans 0..63 so each thread's single f has a unique source)
    const float* wsrc; int ldw; int colof;
    {
        int f = f0 + fl;
        if (f < 192)      { wsrc = w_q;   ldw = 192; colof = f; }
        else if (f < 576) { wsrc = w_kv;  ldw = 384; colof = f - 192; }
        else if (f < 720) { wsrc = w_qp;  ldw = 144; colof = f - 576; }
        else              { wsrc = w_kvp; ldw = 432; colof = f - 720; }
    }

    f32x4 acc0 = {0,0,0,0}, acc1 = {0,0,0,0}, acc2 = {0,0,0,0}, acc3 = {0,0,0,0};

    for (int ks = 0; ks < 12; ++ks) {
        const int kbase = ks * 32;
        // stage A: s f32 -> bf16
        {
            const float* sp = s + (size_t)(m0 + srow) * CSs + kbase + sseg * 8;
            float4 v0 = *(const float4*)sp;
            float4 v1 = *(const float4*)(sp + 4);
            short8v a;
            a[0]=f2bf(v0.x); a[1]=f2bf(v0.y); a[2]=f2bf(v0.z); a[3]=f2bf(v0.w);
            a[4]=f2bf(v1.x); a[5]=f2bf(v1.y); a[6]=f2bf(v1.z); a[7]=f2bf(v1.w);
            *(short8v*)&Al[srow * 40 + sseg * 8] = a;
        }
        // stage B: w f32 -> bf16 (8 k per thread, coalesced across f lanes)
        {
            const float* wp = wsrc + (size_t)(kbase + kk8 * 8) * ldw + colof;
            short8v bv;
#pragma unroll
            for (int j = 0; j < 8; ++j) bv[j] = f2bf(wp[(size_t)j * ldw]);
            *(short8v*)&Bl[fl * 40 + kk8 * 8] = bv;
        }
        __syncthreads();

        short8v av = *(const short8v*)&Al[(16 * w + lrow) * 40 + lkg * 8];
        short8v b0 = *(const short8v*)&Bl[(lrow) * 40 + lkg * 8];
        short8v b1 = *(const short8v*)&Bl[(16 + lrow) * 40 + lkg * 8];
        short8v b2 = *(const short8v*)&Bl[(32 + lrow) * 40 + lkg * 8];
        short8v b3 = *(const short8v*)&Bl[(48 + lrow) * 40 + lkg * 8];
        acc0 = __builtin_amdgcn_mfma_f32_16x16x32_bf16(av, b0, acc0, 0, 0, 0);
        acc1 = __builtin_amdgcn_mfma_f32_16x16x32_bf16(av, b1, acc1, 0, 0, 0);
        acc2 = __builtin_amdgcn_mfma_f32_16x16x32_bf16(av, b2, acc2, 0, 0, 0);
        acc3 = __builtin_amdgcn_mfma_f32_16x16x32_bf16(av, b3, acc3, 0, 0, 0);
        __syncthreads();
    }

    const int orow = m0 + 16 * w + lkg * 4;
#pragma unroll
    for (int e = 0; e < 4; ++e) {
        float* pr = proj + (size_t)(orow + e) * FPROJ + f0;
        int c0 = lrow;
        pr[c0]      = acc0[e] + get_bias(f0 + c0,      b_q, b_kv, b_qp, b_kvp);
        pr[16 + c0] = acc1[e] + get_bias(f0 + 16 + c0, b_q, b_kv, b_qp, b_kvp);
        pr[32 + c0] = acc2[e] + get_bias(f0 + 32 + c0, b_q, b_kv, b_qp, b_kvp);
        pr[48 + c0] = acc3[e] + get_bias(f0 + 48 + c0, b_q, b_kv, b_qp, b_kvp);
    }
}

// ---------------- Kernel 2: pack (r14, unchanged) ----------------
__global__ __launch_bounds__(192) void pack_kernel(
    const float* __restrict__ proj,
    const float* __restrict__ rot, const float* __restrict__ trans,
    const float* __restrict__ hwts, const float* __restrict__ mask,
    short* __restrict__ Ah, short* __restrict__ Al,
    short* __restrict__ Kh, short* __restrict__ Kl,
    short* __restrict__ Vbp)
{
    __shared__ float abuf[12 * 32];
    __shared__ float kbuf[12 * 32];
    __shared__ float vbuf[12 * 40];
    __shared__ float kpsq[12 * 4];

    const int bn = blockIdx.x;
    const int b = bn / Nn;
    const int n = bn % Nn;
    const int t = threadIdx.x;
    const float* R = rot + (size_t)bn * 9;
    const float* T = trans + (size_t)bn * 3;
    const float* pr = proj + (size_t)bn * FPROJ;
    const float mi = mask[bn];

    if (t < 144) {
        float x = pr[720 + t];
        float y = pr[720 + 144 + t];
        float z = pr[720 + 288 + t];
        float ox = R[0]*x + R[1]*y + R[2]*z + T[0];
        float oy = R[3]*x + R[4]*y + R[5]*z + T[1];
        float oz = R[6]*x + R[7]*y + R[8]*z + T[2];
        int h = t / 12, pp = t % 12;
        if (pp < PQq) {
            kbuf[h*32 + 16 + pp*3 + 0] = ox;
            kbuf[h*32 + 16 + pp*3 + 1] = oy;
            kbuf[h*32 + 16 + pp*3 + 2] = oz;
            kpsq[h*4 + pp] = ox*ox + oy*oy + oz*oz;
        } else {
            vbuf[h*40 + 16 + (pp - PQq)*3 + 0] = ox;
            vbuf[h*40 + 16 + (pp - PQq)*3 + 1] = oy;
            vbuf[h*40 + 16 + (pp - PQq)*3 + 2] = oz;
        }
    }
    if (t < 48) {
        float x = pr[576 + t];
        float y = pr[576 + 48 + t];
        float z = pr[576 + 96 + t];
        float ox = R[0]*x + R[1]*y + R[2]*z + T[0];
        float oy = R[3]*x + R[4]*y + R[5]*z + T[1];
        float oz = R[6]*x + R[7]*y + R[8]*z + T[2];
        int h = t / 4, p = t % 4;
        float n2wc = log1pf(expf(hwts[h])) * 0.13608276348795434f;
        abuf[h*32 + 16 + p*3 + 0] = n2wc * ox;
        abuf[h*32 + 16 + p*3 + 1] = n2wc * oy;
        abuf[h*32 + 16 + p*3 + 2] = n2wc * oz;
    }
    {
        int h = t >> 4, c = t & 15;
        abuf[h*32 + c] = 0.28867513459481287f * pr[h * 16 + c];
        kbuf[h*32 + c] = pr[192 + h * 32 + c];
        vbuf[h*40 + c] = pr[192 + h * 32 + 16 + c];
    }
    if (t < 12) {
        abuf[t*32 + 28] = 1.0f;  abuf[t*32 + 29] = mi;
        abuf[t*32 + 30] = 0.0f;  abuf[t*32 + 31] = 0.0f;
        kbuf[t*32 + 29] = INFV * (mi - 1.0f);
        kbuf[t*32 + 30] = 0.0f;  kbuf[t*32 + 31] = 0.0f;
    }
    __syncthreads();
    if (t < 12) {
        float hw2 = log1pf(expf(hwts[t]));
        float wc = -0.5f * hw2 * 0.13608276348795434f;
        kbuf[t*32 + 28] = wc * (kpsq[t*4] + kpsq[t*4+1] + kpsq[t*4+2] + kpsq[t*4+3]);
    }
    __syncthreads();

    if (t < 48) {
        int h = t >> 2, pc = t & 3;
        const float* src = &abuf[h*32 + pc*8];
        short8v hi, lo;
#pragma unroll
        for (int k = 0; k < 8; ++k) {
            short hh = f2bf(src[k]);
            hi[k] = hh; lo[k] = f2bf(src[k] - bf2f(hh));
        }
        size_t off = ((size_t)((b * Hh + h) * Nn + n)) * 32 + pc * 8;
        *(short8v*)&Ah[off] = hi;
        *(short8v*)&Al[off] = lo;
    } else if (t < 96) {
        int tt = t - 48, h = tt >> 2, pc = tt & 3;
        const float* src = &kbuf[h*32 + pc*8];
        short8v hi, lo;
#pragma unroll
        for (int k = 0; k < 8; ++k) {
            short hh = f2bf(src[k]);
            hi[k] = hh; lo[k] = f2bf(src[k] - bf2f(hh));
        }
        size_t off = ((size_t)((b * Hh + h) * Nn + n)) * 32 + pc * 8;
        *(short8v*)&Kh[off] = hi;
        *(short8v*)&Kl[off] = lo;
    } else if (t < 156) {
        int tt = t - 96, h = tt / 5, pc = tt % 5;
        const float* src = &vbuf[h*40 + pc*8];
        short8v v;
#pragma unroll
        for (int k = 0; k < 8; ++k) v[k] = f2bf(src[k]);
        *(short8v*)&Vbp[((size_t)((b * Hh + h) * Nn + n)) * 40 + pc * 8] = v;
    }
}

// ---------------- Kernel 3: attention partial + last-block merge ----------------
__global__ __launch_bounds__(256) void attn_part_kernel(
    const short* __restrict__ Ah, const short* __restrict__ Al,
    const short* __restrict__ Kh, const short* __restrict__ Kl,
    const short* __restrict__ Vbp,
    const float* __restrict__ rot, const float* __restrict__ trans,
    float* __restrict__ part, int* __restrict__ cnt,
    short* __restrict__ cat_bf)
{
    __shared__ short smem_s[13696];
    __shared__ int is_last;
    short* Ahi = smem_s;
    short* Alo = smem_s + 2560;
    short* Khi = smem_s + 5120;
    short* Klo = smem_s + 7680;
    short* Vb  = smem_s + 10240;
    short* Pb  = smem_s;

    const int bid = blockIdx.x;
    const int jc = bid % 6;
    const int ic = (bid / 6) % 6;
    const int h  = (bid / 36) % Hh;
    const int b  = bid / (36 * Hh);
    const int t  = threadIdx.x;
    const int i0 = ic * 64;
    const int j0 = jc * 64;
    const int bh = b * Hh + h;
    const int g  = bh * 6 + ic;          // merge group

    const short* AhB = Ah + ((size_t)(bh * Nn + i0)) * 32;
    const short* AlB = Al + ((size_t)(bh * Nn + i0)) * 32;
    const short* KhB = Kh + ((size_t)(bh * Nn + j0)) * 32;
    const short* KlB = Kl + ((size_t)(bh * Nn + j0)) * 32;
    const short* VbB = Vbp + ((size_t)(bh * Nn + j0)) * 40;

    {
        const int i = t >> 2, pc = t & 3;
        *(short8v*)&Ahi[i * 40 + pc * 8] = *(const short8v*)&AhB[i * 32 + pc * 8];
        *(short8v*)&Alo[i * 40 + pc * 8] = *(const short8v*)&AlB[i * 32 + pc * 8];
        *(short8v*)&Khi[i * 40 + pc * 8] = *(const short8v*)&KhB[i * 32 + pc * 8];
        *(short8v*)&Klo[i * 40 + pc * 8] = *(const short8v*)&KlB[i * 32 + pc * 8];
    }
#pragma unroll
    for (int e = t; e < 320; e += 256) {
        int j = e / 5, pc = e % 5;
        short8v v = *(const short8v*)&VbB[j * 40 + pc * 8];
#pragma unroll
        for (int k = 0; k < 8; ++k) Vb[(pc * 8 + k) * 72 + j] = v[k];
    }
    if (t < 144) {
        int o = 40 * 72 + t * 4;
        Vb[o] = 0; Vb[o+1] = 0; Vb[o+2] = 0; Vb[o+3] = 0;
    }
    __syncthreads();

    const int w = t >> 6;
    const int lane = t & 63;
    const int lrow = lane & 15;
    const int lkg  = lane >> 4;

    f32x4 La0 = {0,0,0,0}, La1 = {0,0,0,0}, La2 = {0,0,0,0}, La3 = {0,0,0,0};
    {
        short8v ahi = *(const short8v*)&Ahi[(16 * w + lrow) * 40 + lkg * 8];
        short8v alo = *(const short8v*)&Alo[(16 * w + lrow) * 40 + lkg * 8];
        short8v k0h = *(const short8v*)&Khi[(lrow) * 40 + lkg * 8];
        short8v k1h = *(const short8v*)&Khi[(16 + lrow) * 40 + lkg * 8];
        short8v k2h = *(const short8v*)&Khi[(32 + lrow) * 40 + lkg * 8];
        short8v k3h = *(const short8v*)&Khi[(48 + lrow) * 40 + lkg * 8];
        short8v k0l = *(const short8v*)&Klo[(lrow) * 40 + lkg * 8];
        short8v k1l = *(const short8v*)&Klo[(16 + lrow) * 40 + lkg * 8];
        short8v k2l = *(const short8v*)&Klo[(32 + lrow) * 40 + lkg * 8];
        short8v k3l = *(const short8v*)&Klo[(48 + lrow) * 40 + lkg * 8];
        La0 = __builtin_amdgcn_mfma_f32_16x16x32_bf16(ahi, k0h, La0, 0, 0, 0);
        La1 = __builtin_amdgcn_mfma_f32_16x16x32_bf16(ahi, k1h, La1, 0, 0, 0);
        La2 = __builtin_amdgcn_mfma_f32_16x16x32_bf16(ahi, k2h, La2, 0, 0, 0);
        La3 = __builtin_amdgcn_mfma_f32_16x16x32_bf16(ahi, k3h, La3, 0, 0, 0);
        La0 = __builtin_amdgcn_mfma_f32_16x16x32_bf16(alo, k0h, La0, 0, 0, 0);
        La1 = __builtin_amdgcn_mfma_f32_16x16x32_bf16(alo, k1h, La1, 0, 0, 0);
        La2 = __builtin_amdgcn_mfma_f32_16x16x32_bf16(alo, k2h, La2, 0, 0, 0);
        La3 = __builtin_amdgcn_mfma_f32_16x16x32_bf16(alo, k3h, La3, 0, 0, 0);
        La0 = __builtin_amdgcn_mfma_f32_16x16x32_bf16(ahi, k0l, La0, 0, 0, 0);
        La1 = __builtin_amdgcn_mfma_f32_16x16x32_bf16(ahi, k1l, La1, 0, 0, 0);
        La2 = __builtin_amdgcn_mfma_f32_16x16x32_bf16(ahi, k2l, La2, 0, 0, 0);
        La3 = __builtin_amdgcn_mfma_f32_16x16x32_bf16(ahi, k3l, La3, 0, 0, 0);
    }

    float* po = part + (size_t)(g * 6 + jc) * PSTRIDE;
    short* poO = (short*)po;

    float m0_, m1_, m2_, m3_, s0_, s1_, s2_, s3_;
    float p00,p10,p20,p30, p01,p11,p21,p31, p02,p12,p22,p32, p03,p13,p23,p33;

#define SMAX_E(E, TM, SM, P0, P1, P2, P3) { \
    float tmax_ = fmaxf(fmaxf(La0[E], La1[E]), fmaxf(La2[E], La3[E])); \
    tmax_ = fmaxf(tmax_, __shfl_xor(tmax_, 1)); \
    tmax_ = fmaxf(tmax_, __shfl_xor(tmax_, 2)); \
    tmax_ = fmaxf(tmax_, __shfl_xor(tmax_, 4)); \
    tmax_ = fmaxf(tmax_, __shfl_xor(tmax_, 8)); \
    P0 = __expf(La0[E] - tmax_); P1 = __expf(La1[E] - tmax_); \
    P2 = __expf(La2[E] - tmax_); P3 = __expf(La3[E] - tmax_); \
    float cs_ = P0 + P1 + P2 + P3; \
    cs_ += __shfl_xor(cs_, 1); cs_ += __shfl_xor(cs_, 2); \
    cs_ += __shfl_xor(cs_, 4); cs_ += __shfl_xor(cs_, 8); \
    TM = tmax_; SM = cs_; }

    SMAX_E(0, m0_, s0_, p00, p10, p20, p30);
    SMAX_E(1, m1_, s1_, p01, p11, p21, p31);
    SMAX_E(2, m2_, s2_, p02, p12, p22, p32);
    SMAX_E(3, m3_, s3_, p03, p13, p23, p33);
#undef SMAX_E

    if (lrow == 0) {
        int rb = 16 * w + 4 * lkg;
        po[1280 + rb + 0] = m0_; po[1344 + rb + 0] = s0_;
        po[1280 + rb + 1] = m1_; po[1344 + rb + 1] = s1_;
        po[1280 + rb + 2] = m2_; po[1344 + rb + 2] = s2_;
        po[1280 + rb + 3] = m3_; po[1344 + rb + 3] = s3_;
    }
    __syncthreads();

#define PW(E, PJ0, PJ1, PJ2, PJ3) { \
    int r_ = (16 * w + 4 * lkg + E) * 72; \
    Pb[r_ + lrow]      = f2bf(PJ0); \
    Pb[r_ + 16 + lrow] = f2bf(PJ1); \
    Pb[r_ + 32 + lrow] = f2bf(PJ2); \
    Pb[r_ + 48 + lrow] = f2bf(PJ3); }
    PW(0, p00, p10, p20, p30);
    PW(1, p01, p11, p21, p31);
    PW(2, p02, p12, p22, p32);
    PW(3, p03, p13, p23, p33);
#undef PW
    __syncthreads();

    f32x4 O0 = {0,0,0,0}, O1 = {0,0,0,0}, O2 = {0,0,0,0};
#pragma unroll
    for (int ch = 0; ch < 2; ++ch) {
        short8v pf = *(const short8v*)&Pb[(16 * w + lrow) * 72 + ch * 32 + lkg * 8];
        short8v v0 = *(const short8v*)&Vb[(lrow) * 72 + ch * 32 + lkg * 8];
        short8v v1 = *(const short8v*)&Vb[(16 + lrow) * 72 + ch * 32 + lkg * 8];
        short8v v2 = *(const short8v*)&Vb[(32 + lrow) * 72 + ch * 32 + lkg * 8];
        O0 = __builtin_amdgcn_mfma_f32_16x16x32_bf16(pf, v0, O0, 0, 0, 0);
        O1 = __builtin_amdgcn_mfma_f32_16x16x32_bf16(pf, v1, O1, 0, 0, 0);
        O2 = __builtin_amdgcn_mfma_f32_16x16x32_bf16(pf, v2, O2, 0, 0, 0);
    }
#pragma unroll
    for (int e = 0; e < 4; ++e) {
        int r = 16 * w + 4 * lkg + e;
        poO[r * 40 + lrow]      = f2bf(O0[e]);
        poO[r * 40 + 16 + lrow] = f2bf(O1[e]);
        if (lrow < 8) poO[r * 40 + 32 + lrow] = f2bf(O2[e]);
    }

    // ---- last-block-done gate (release: syncthreads drains vmcnt; fence flushes L2) ----
    __syncthreads();
    if (t == 0) {
        __threadfence();
        is_last = (atomicAdd(&cnt[g], 1) == 5);
    }
    __syncthreads();
    if (!is_last) return;
    __threadfence();   // acquire: invalidate L2 before reading peers' partials

    // ---- merge phase (r14 merge body; LDS aliased onto smem_s) ----
    float* wsh = (float*)smem_s;        // 512 floats
    float* ob  = (float*)smem_s + 512;  // 2816 floats
    const size_t pbase = (size_t)g * 6 * PSTRIDE;

    if (t < 64) {
        float mk[6], sk[6];
        float M = -3.0e38f;
#pragma unroll
        for (int k = 0; k < 6; ++k) {
            mk[k] = part[pbase + (size_t)k * PSTRIDE + 1280 + t];
            sk[k] = part[pbase + (size_t)k * PSTRIDE + 1344 + t];
            M = fmaxf(M, mk[k]);
        }
        float wk[6]; float stot = 0.0f;
#pragma unroll
        for (int k = 0; k < 6; ++k) {
            wk[k] = __expf(mk[k] - M);
            stot += wk[k] * sk[k];
        }
        float inv = 1.0f / stot;
#pragma unroll
        for (int k = 0; k < 6; ++k) wsh[t * 8 + k] = wk[k] * inv;
    }
    __syncthreads();

#pragma unroll
    for (int it = 0; it < 10; ++it) {
        int idx = t + it * 256;
        int row = idx / 40, col = idx % 40;
        float v = 0.0f;
#pragma unroll
        for (int k = 0; k < 6; ++k) {
            const short* pO = (const short*)&part[pbase + (size_t)k * PSTRIDE];
            v += wsh[row * 8 + k] * bf2f(pO[row * 40 + col]);
        }
        ob[row * 44 + col] = v;
    }
    __syncthreads();

    {
        const int i = t >> 2;
        const int qq = t & 3;
        const int bnI = b * Nn + i0 + i;
        short* crow = cat_bf + (size_t)bnI * FCAT;

        float o0 = ob[i * 44 + 4 * qq + 0];
        float o1 = ob[i * 44 + 4 * qq + 1];
        float o2 = ob[i * 44 + 4 * qq + 2];
        float o3 = ob[i * 44 + 4 * qq + 3];
        crow[h * 16 + 4 * qq + 0] = f2bf(o0);
        crow[h * 16 + 4 * qq + 1] = f2bf(o1);
        crow[h * 16 + 4 * qq + 2] = f2bf(o2);
        crow[h * 16 + 4 * qq + 3] = f2bf(o3);

        const float* R = rot + (size_t)bnI * 9;
        const float* T = trans + (size_t)bnI * 3;
#pragma unroll
        for (int e = 0; e < 2; ++e) {
            int pe = qq + 4 * e;
            float g0 = ob[i * 44 + 16 + 3 * pe + 0] - T[0];
            float g1 = ob[i * 44 + 16 + 3 * pe + 1] - T[1];
            float g2 = ob[i * 44 + 16 + 3 * pe + 2] - T[2];
            float lx = R[0]*g0 + R[3]*g1 + R[6]*g2;
            float ly = R[1]*g0 + R[4]*g1 + R[7]*g2;
            float lz = R[2]*g0 + R[5]*g1 + R[8]*g2;
            crow[192 + h * 8 + pe] = f2bf(lx);
            crow[288 + h * 8 + pe] = f2bf(ly);
            crow[384 + h * 8 + pe] = f2bf(lz);
            crow[480 + h * 8 + pe] = f2bf(sqrtf(lx*lx + ly*ly + lz*lz + EPSV));
        }
    }
}

// ---------------- Kernel 4: output GEMM via bf16 MFMA (in-kernel w_out conversion) ----------------
// grid 288 = 48 bm x 6 bn; 256 thr. 32x64 tiles.
__global__ __launch_bounds__(256) void out_kernel(
    const short* __restrict__ cat_bf, const float* __restrict__ w_out,
    const float* __restrict__ b_out, float* __restrict__ out)
{
    __shared__ short Al[32 * 40];
    __shared__ short Bl[64 * 40];

    const int bm = blockIdx.x % 48;
    const int bn = blockIdx.x / 48;
    const int m0 = bm * 32;
    const int n0 = bn * 64;
    const int t = threadIdx.x;
    const int w = t >> 6;
    const int lane = t & 63;
    const int lrow = lane & 15;
    const int lkg  = lane >> 4;
    const int r0 = 16 * (w & 1);
    const int c0 = 32 * (w >> 1);
    const int nl  = t & 63;          // B staging: n lane
    const int kk8 = t >> 6;          // 0..3

    f32x4 acc0 = {0,0,0,0}, acc1 = {0,0,0,0};

    for (int ks = 0; ks < 18; ++ks) {
        const int kbase = ks * 32;
        if (t < 128) {
            int arow = t >> 2, aseg = t & 3;
            *(short8v*)&Al[arow * 40 + aseg * 8] =
                *(const short8v*)&cat_bf[(size_t)(m0 + arow) * FCAT + kbase + aseg * 8];
        }
        {
            const float* wp = w_out + (size_t)(kbase + kk8 * 8) * 384 + n0 + nl;
            short8v bv;
#pragma unroll
            for (int j = 0; j < 8; ++j) bv[j] = f2bf(wp[(size_t)j * 384]);
            *(short8v*)&Bl[nl * 40 + kk8 * 8] = bv;
        }
        __syncthreads();

        short8v av = *(const short8v*)&Al[(r0 + lrow) * 40 + lkg * 8];
        short8v b0 = *(const short8v*)&Bl[(c0 + lrow) * 40 + lkg * 8];
        short8v b1 = *(const short8v*)&Bl[(c0 + 16 + lrow) * 40 + lkg * 8];
        acc0 = __builtin_amdgcn_mfma_f32_16x16x32_bf16(av, b0, acc0, 0, 0, 0);
        acc1 = __builtin_amdgcn_mfma_f32_16x16x32_bf16(av, b1, acc1, 0, 0, 0);
        __syncthreads();
    }

    const int orow = m0 + r0 + lkg * 4;
#pragma unroll
    for (int e = 0; e < 4; ++e) {
        float* pr = out + (size_t)(orow + e) * 384 + n0 + c0;
        pr[lrow]      = acc0[e] + b_out[n0 + c0 + lrow];
        pr[16 + lrow] = acc1[e] + b_out[n0 + c0 + 16 + lrow];
    }
}

extern "C" void kernel_launch(void* const* d_in, const int* in_sizes, int n_in,
                              void* d_out, int out_size, void* d_ws, size_t ws_size,
                              hipStream_t stream) {
    const float* s     = (const float*)d_in[0];
    const float* rot   = (const float*)d_in[2];
    const float* trans = (const float*)d_in[3];
    const float* mask  = (const float*)d_in[4];
    const float* w_q   = (const float*)d_in[5];
    const float* b_q   = (const float*)d_in[6];
    const float* w_kv  = (const float*)d_in[7];
    const float* b_kv  = (const float*)d_in[8];
    const float* w_qp  = (const float*)d_in[13];
    const float* b_qp  = (const float*)d_in[14];
    const float* w_kvp = (const float*)d_in[15];
    const float* b_kvp = (const float*)d_in[16];
    const float* hwts  = (const float*)d_in[17];
    const float* w_out = (const float*)d_in[18];
    const float* b_out = (const float*)d_in[19];

    float* ws     = (float*)d_ws;
    float* proj   = ws + WS_PROJ;
    short* cat_bf = (short*)(ws + WS_CAT);
    float* partb  = ws + WS_PART;
    int*   cnt    = (int*)(ws + WS_CNT);
    short* Ah     = (short*)(ws + WS_AH);
    short* Alp    = (short*)(ws + WS_AL);
    short* Kh     = (short*)(ws + WS_KH);
    short* Kl     = (short*)(ws + WS_KL);
    short* Vbp    = (short*)(ws + WS_VBP);
    float* out    = (float*)d_out;

    hipMemsetAsync(cnt, 0, 288 * sizeof(int), stream);
    hipLaunchKernelGGL(proj_kernel, dim3(432), dim3(256), 0, stream,
                       s, w_q, w_kv, w_qp, w_kvp, b_q, b_kv, b_qp, b_kvp, proj);
    hipLaunchKernelGGL(pack_kernel, dim3(1536), dim3(192), 0, stream,
                       proj, rot, trans, hwts, mask, Ah, Alp, Kh, Kl, Vbp);
    hipLaunchKernelGGL(attn_part_kernel, dim3(1728), dim3(256), 0, stream,
                       Ah, Alp, Kh, Kl, Vbp, rot, trans, partb, cnt, cat_bf);
    hipLaunchKernelGGL(out_kernel, dim3(288), dim3(256), 0, stream,
                       cat_bf, w_out, b_out, out);
}

// Round 16
// 54.159 us; speedup vs baseline: 3.8528x; 3.8528x over previous
//
#include <hip/hip_runtime.h>
#include <math.h>

#define Bb 4
#define Nn 384
#define CSs 384
#define Hh 12
#define Cc 16
#define PQq 4
#define PVv 8
#define FPROJ 1152
#define FCAT 576
#define INFV 100000.0f
#define EPSV 1e-8f

// ws layout (float slots)
#define WS_PROJ 0
#define WS_CAT  3022848      // bf16 cat: 1536*576 shorts
#define WS_PART 4423680      // 48*36 partials, stride 1408 (O bf16 [64][40] | m[64]@1280 | s[64]@1344)
#define PSTRIDE 1408
#define WS_AH   9400320
#define WS_AL   9695232
#define WS_KH   9990144
#define WS_KL   10285056
#define WS_VBP  10579968     // 48*384*40 shorts

typedef __attribute__((ext_vector_type(8))) short short8v;
typedef __attribute__((ext_vector_type(4))) float f32x4;

__device__ __forceinline__ short f2bf(float x) {
    unsigned u = __float_as_uint(x);
    unsigned r = (u + 0x7FFFu + ((u >> 16) & 1u)) >> 16;
    return (short)r;
}
__device__ __forceinline__ float bf2f(short h) {
    return __uint_as_float(((unsigned)(unsigned short)h) << 16);
}

__device__ __forceinline__ float get_bias(int f,
    const float* __restrict__ b_q, const float* __restrict__ b_kv,
    const float* __restrict__ b_qp, const float* __restrict__ b_kvp)
{
    if (f < 192) return b_q[f];
    if (f < 576) return b_kv[f - 192];
    if (f < 720) return b_qp[f - 576];
    return b_kvp[f - 720];
}

// ---------------- Kernel 1: projection GEMM via bf16 MFMA (in-kernel conversions) ----------------
__global__ __launch_bounds__(256) void proj_kernel(
    const float* __restrict__ s,
    const float* __restrict__ w_q, const float* __restrict__ w_kv,
    const float* __restrict__ w_qp, const float* __restrict__ w_kvp,
    const float* __restrict__ b_q, const float* __restrict__ b_kv,
    const float* __restrict__ b_qp, const float* __restrict__ b_kvp,
    float* __restrict__ proj)
{
    __shared__ short Al[64 * 40];
    __shared__ short Bl[64 * 40];

    const int bm = blockIdx.x % 24;
    const int bn = blockIdx.x / 24;
    const int m0 = bm * 64;
    const int f0 = bn * 64;
    const int t = threadIdx.x;
    const int w = t >> 6;
    const int lane = t & 63;
    const int lrow = lane & 15;
    const int lkg  = lane >> 4;

    const int srow = t >> 2;
    const int sseg = t & 3;
    const int fl   = t & 63;
    const int kk8  = t >> 6;

    const float* wsrc; int ldw; int colof;
    {
        int f = f0 + fl;
        if (f < 192)      { wsrc = w_q;   ldw = 192; colof = f; }
        else if (f < 576) { wsrc = w_kv;  ldw = 384; colof = f - 192; }
        else if (f < 720) { wsrc = w_qp;  ldw = 144; colof = f - 576; }
        else              { wsrc = w_kvp; ldw = 432; colof = f - 720; }
    }

    f32x4 acc0 = {0,0,0,0}, acc1 = {0,0,0,0}, acc2 = {0,0,0,0}, acc3 = {0,0,0,0};

    for (int ks = 0; ks < 12; ++ks) {
        const int kbase = ks * 32;
        {
            const float* sp = s + (size_t)(m0 + srow) * CSs + kbase + sseg * 8;
            float4 v0 = *(const float4*)sp;
            float4 v1 = *(const float4*)(sp + 4);
            short8v a;
            a[0]=f2bf(v0.x); a[1]=f2bf(v0.y); a[2]=f2bf(v0.z); a[3]=f2bf(v0.w);
            a[4]=f2bf(v1.x); a[5]=f2bf(v1.y); a[6]=f2bf(v1.z); a[7]=f2bf(v1.w);
            *(short8v*)&Al[srow * 40 + sseg * 8] = a;
        }
        {
            const float* wp = wsrc + (size_t)(kbase + kk8 * 8) * ldw + colof;
            short8v bv;
#pragma unroll
            for (int j = 0; j < 8; ++j) bv[j] = f2bf(wp[(size_t)j * ldw]);
            *(short8v*)&Bl[fl * 40 + kk8 * 8] = bv;
        }
        __syncthreads();

        short8v av = *(const short8v*)&Al[(16 * w + lrow) * 40 + lkg * 8];
        short8v b0 = *(const short8v*)&Bl[(lrow) * 40 + lkg * 8];
        short8v b1 = *(const short8v*)&Bl[(16 + lrow) * 40 + lkg * 8];
        short8v b2 = *(const short8v*)&Bl[(32 + lrow) * 40 + lkg * 8];
        short8v b3 = *(const short8v*)&Bl[(48 + lrow) * 40 + lkg * 8];
        acc0 = __builtin_amdgcn_mfma_f32_16x16x32_bf16(av, b0, acc0, 0, 0, 0);
        acc1 = __builtin_amdgcn_mfma_f32_16x16x32_bf16(av, b1, acc1, 0, 0, 0);
        acc2 = __builtin_amdgcn_mfma_f32_16x16x32_bf16(av, b2, acc2, 0, 0, 0);
        acc3 = __builtin_amdgcn_mfma_f32_16x16x32_bf16(av, b3, acc3, 0, 0, 0);
        __syncthreads();
    }

    const int orow = m0 + 16 * w + lkg * 4;
#pragma unroll
    for (int e = 0; e < 4; ++e) {
        float* pr = proj + (size_t)(orow + e) * FPROJ + f0;
        int c0 = lrow;
        pr[c0]      = acc0[e] + get_bias(f0 + c0,      b_q, b_kv, b_qp, b_kvp);
        pr[16 + c0] = acc1[e] + get_bias(f0 + 16 + c0, b_q, b_kv, b_qp, b_kvp);
        pr[32 + c0] = acc2[e] + get_bias(f0 + 32 + c0, b_q, b_kv, b_qp, b_kvp);
        pr[48 + c0] = acc3[e] + get_bias(f0 + 48 + c0, b_q, b_kv, b_qp, b_kvp);
    }
}

// ---------------- Kernel 2: pack (r14, unchanged) ----------------
__global__ __launch_bounds__(192) void pack_kernel(
    const float* __restrict__ proj,
    const float* __restrict__ rot, const float* __restrict__ trans,
    const float* __restrict__ hwts, const float* __restrict__ mask,
    short* __restrict__ Ah, short* __restrict__ Al,
    short* __restrict__ Kh, short* __restrict__ Kl,
    short* __restrict__ Vbp)
{
    __shared__ float abuf[12 * 32];
    __shared__ float kbuf[12 * 32];
    __shared__ float vbuf[12 * 40];
    __shared__ float kpsq[12 * 4];

    const int bn = blockIdx.x;
    const int b = bn / Nn;
    const int n = bn % Nn;
    const int t = threadIdx.x;
    const float* R = rot + (size_t)bn * 9;
    const float* T = trans + (size_t)bn * 3;
    const float* pr = proj + (size_t)bn * FPROJ;
    const float mi = mask[bn];

    if (t < 144) {
        float x = pr[720 + t];
        float y = pr[720 + 144 + t];
        float z = pr[720 + 288 + t];
        float ox = R[0]*x + R[1]*y + R[2]*z + T[0];
        float oy = R[3]*x + R[4]*y + R[5]*z + T[1];
        float oz = R[6]*x + R[7]*y + R[8]*z + T[2];
        int h = t / 12, pp = t % 12;
        if (pp < PQq) {
            kbuf[h*32 + 16 + pp*3 + 0] = ox;
            kbuf[h*32 + 16 + pp*3 + 1] = oy;
            kbuf[h*32 + 16 + pp*3 + 2] = oz;
            kpsq[h*4 + pp] = ox*ox + oy*oy + oz*oz;
        } else {
            vbuf[h*40 + 16 + (pp - PQq)*3 + 0] = ox;
            vbuf[h*40 + 16 + (pp - PQq)*3 + 1] = oy;
            vbuf[h*40 + 16 + (pp - PQq)*3 + 2] = oz;
        }
    }
    if (t < 48) {
        float x = pr[576 + t];
        float y = pr[576 + 48 + t];
        float z = pr[576 + 96 + t];
        float ox = R[0]*x + R[1]*y + R[2]*z + T[0];
        float oy = R[3]*x + R[4]*y + R[5]*z + T[1];
        float oz = R[6]*x + R[7]*y + R[8]*z + T[2];
        int h = t / 4, p = t % 4;
        float n2wc = log1pf(expf(hwts[h])) * 0.13608276348795434f;
        abuf[h*32 + 16 + p*3 + 0] = n2wc * ox;
        abuf[h*32 + 16 + p*3 + 1] = n2wc * oy;
        abuf[h*32 + 16 + p*3 + 2] = n2wc * oz;
    }
    {
        int h = t >> 4, c = t & 15;
        abuf[h*32 + c] = 0.28867513459481287f * pr[h * 16 + c];
        kbuf[h*32 + c] = pr[192 + h * 32 + c];
        vbuf[h*40 + c] = pr[192 + h * 32 + 16 + c];
    }
    if (t < 12) {
        abuf[t*32 + 28] = 1.0f;  abuf[t*32 + 29] = mi;
        abuf[t*32 + 30] = 0.0f;  abuf[t*32 + 31] = 0.0f;
        kbuf[t*32 + 29] = INFV * (mi - 1.0f);
        kbuf[t*32 + 30] = 0.0f;  kbuf[t*32 + 31] = 0.0f;
    }
    __syncthreads();
    if (t < 12) {
        float hw2 = log1pf(expf(hwts[t]));
        float wc = -0.5f * hw2 * 0.13608276348795434f;
        kbuf[t*32 + 28] = wc * (kpsq[t*4] + kpsq[t*4+1] + kpsq[t*4+2] + kpsq[t*4+3]);
    }
    __syncthreads();

    if (t < 48) {
        int h = t >> 2, pc = t & 3;
        const float* src = &abuf[h*32 + pc*8];
        short8v hi, lo;
#pragma unroll
        for (int k = 0; k < 8; ++k) {
            short hh = f2bf(src[k]);
            hi[k] = hh; lo[k] = f2bf(src[k] - bf2f(hh));
        }
        size_t off = ((size_t)((b * Hh + h) * Nn + n)) * 32 + pc * 8;
        *(short8v*)&Ah[off] = hi;
        *(short8v*)&Al[off] = lo;
    } else if (t < 96) {
        int tt = t - 48, h = tt >> 2, pc = tt & 3;
        const float* src = &kbuf[h*32 + pc*8];
        short8v hi, lo;
#pragma unroll
        for (int k = 0; k < 8; ++k) {
            short hh = f2bf(src[k]);
            hi[k] = hh; lo[k] = f2bf(src[k] - bf2f(hh));
        }
        size_t off = ((size_t)((b * Hh + h) * Nn + n)) * 32 + pc * 8;
        *(short8v*)&Kh[off] = hi;
        *(short8v*)&Kl[off] = lo;
    } else if (t < 156) {
        int tt = t - 96, h = tt / 5, pc = tt % 5;
        const float* src = &vbuf[h*40 + pc*8];
        short8v v;
#pragma unroll
        for (int k = 0; k < 8; ++k) v[k] = f2bf(src[k]);
        *(short8v*)&Vbp[((size_t)((b * Hh + h) * Nn + n)) * 40 + pc * 8] = v;
    }
}

// ---------------- Kernel 3a: attention partial via MFMA (r14, no fences) ----------------
__global__ __launch_bounds__(256) void attn_part_kernel(
    const short* __restrict__ Ah, const short* __restrict__ Al,
    const short* __restrict__ Kh, const short* __restrict__ Kl,
    const short* __restrict__ Vbp,
    float* __restrict__ part)
{
    __shared__ short smem_s[13696];
    short* Ahi = smem_s;
    short* Alo = smem_s + 2560;
    short* Khi = smem_s + 5120;
    short* Klo = smem_s + 7680;
    short* Vb  = smem_s + 10240;
    short* Pb  = smem_s;

    const int bid = blockIdx.x;
    const int jc = bid % 6;
    const int ic = (bid / 6) % 6;
    const int h  = (bid / 36) % Hh;
    const int b  = bid / (36 * Hh);
    const int t  = threadIdx.x;
    const int i0 = ic * 64;
    const int j0 = jc * 64;
    const int bh = b * Hh + h;

    const short* AhB = Ah + ((size_t)(bh * Nn + i0)) * 32;
    const short* AlB = Al + ((size_t)(bh * Nn + i0)) * 32;
    const short* KhB = Kh + ((size_t)(bh * Nn + j0)) * 32;
    const short* KlB = Kl + ((size_t)(bh * Nn + j0)) * 32;
    const short* VbB = Vbp + ((size_t)(bh * Nn + j0)) * 40;

    {
        const int i = t >> 2, pc = t & 3;
        *(short8v*)&Ahi[i * 40 + pc * 8] = *(const short8v*)&AhB[i * 32 + pc * 8];
        *(short8v*)&Alo[i * 40 + pc * 8] = *(const short8v*)&AlB[i * 32 + pc * 8];
        *(short8v*)&Khi[i * 40 + pc * 8] = *(const short8v*)&KhB[i * 32 + pc * 8];
        *(short8v*)&Klo[i * 40 + pc * 8] = *(const short8v*)&KlB[i * 32 + pc * 8];
    }
#pragma unroll
    for (int e = t; e < 320; e += 256) {
        int j = e / 5, pc = e % 5;
        short8v v = *(const short8v*)&VbB[j * 40 + pc * 8];
#pragma unroll
        for (int k = 0; k < 8; ++k) Vb[(pc * 8 + k) * 72 + j] = v[k];
    }
    if (t < 144) {
        int o = 40 * 72 + t * 4;
        Vb[o] = 0; Vb[o+1] = 0; Vb[o+2] = 0; Vb[o+3] = 0;
    }
    __syncthreads();

    const int w = t >> 6;
    const int lane = t & 63;
    const int lrow = lane & 15;
    const int lkg  = lane >> 4;

    f32x4 La0 = {0,0,0,0}, La1 = {0,0,0,0}, La2 = {0,0,0,0}, La3 = {0,0,0,0};
    {
        short8v ahi = *(const short8v*)&Ahi[(16 * w + lrow) * 40 + lkg * 8];
        short8v alo = *(const short8v*)&Alo[(16 * w + lrow) * 40 + lkg * 8];
        short8v k0h = *(const short8v*)&Khi[(lrow) * 40 + lkg * 8];
        short8v k1h = *(const short8v*)&Khi[(16 + lrow) * 40 + lkg * 8];
        short8v k2h = *(const short8v*)&Khi[(32 + lrow) * 40 + lkg * 8];
        short8v k3h = *(const short8v*)&Khi[(48 + lrow) * 40 + lkg * 8];
        short8v k0l = *(const short8v*)&Klo[(lrow) * 40 + lkg * 8];
        short8v k1l = *(const short8v*)&Klo[(16 + lrow) * 40 + lkg * 8];
        short8v k2l = *(const short8v*)&Klo[(32 + lrow) * 40 + lkg * 8];
        short8v k3l = *(const short8v*)&Klo[(48 + lrow) * 40 + lkg * 8];
        La0 = __builtin_amdgcn_mfma_f32_16x16x32_bf16(ahi, k0h, La0, 0, 0, 0);
        La1 = __builtin_amdgcn_mfma_f32_16x16x32_bf16(ahi, k1h, La1, 0, 0, 0);
        La2 = __builtin_amdgcn_mfma_f32_16x16x32_bf16(ahi, k2h, La2, 0, 0, 0);
        La3 = __builtin_amdgcn_mfma_f32_16x16x32_bf16(ahi, k3h, La3, 0, 0, 0);
        La0 = __builtin_amdgcn_mfma_f32_16x16x32_bf16(alo, k0h, La0, 0, 0, 0);
        La1 = __builtin_amdgcn_mfma_f32_16x16x32_bf16(alo, k1h, La1, 0, 0, 0);
        La2 = __builtin_amdgcn_mfma_f32_16x16x32_bf16(alo, k2h, La2, 0, 0, 0);
        La3 = __builtin_amdgcn_mfma_f32_16x16x32_bf16(alo, k3h, La3, 0, 0, 0);
        La0 = __builtin_amdgcn_mfma_f32_16x16x32_bf16(ahi, k0l, La0, 0, 0, 0);
        La1 = __builtin_amdgcn_mfma_f32_16x16x32_bf16(ahi, k1l, La1, 0, 0, 0);
        La2 = __builtin_amdgcn_mfma_f32_16x16x32_bf16(ahi, k2l, La2, 0, 0, 0);
        La3 = __builtin_amdgcn_mfma_f32_16x16x32_bf16(ahi, k3l, La3, 0, 0, 0);
    }

    const size_t pidx = ((size_t)(bh * 6 + ic)) * 6 + jc;
    float* po = part + pidx * PSTRIDE;
    short* poO = (short*)po;

    float m0_, m1_, m2_, m3_, s0_, s1_, s2_, s3_;
    float p00,p10,p20,p30, p01,p11,p21,p31, p02,p12,p22,p32, p03,p13,p23,p33;

#define SMAX_E(E, TM, SM, P0, P1, P2, P3) { \
    float tmax_ = fmaxf(fmaxf(La0[E], La1[E]), fmaxf(La2[E], La3[E])); \
    tmax_ = fmaxf(tmax_, __shfl_xor(tmax_, 1)); \
    tmax_ = fmaxf(tmax_, __shfl_xor(tmax_, 2)); \
    tmax_ = fmaxf(tmax_, __shfl_xor(tmax_, 4)); \
    tmax_ = fmaxf(tmax_, __shfl_xor(tmax_, 8)); \
    P0 = __expf(La0[E] - tmax_); P1 = __expf(La1[E] - tmax_); \
    P2 = __expf(La2[E] - tmax_); P3 = __expf(La3[E] - tmax_); \
    float cs_ = P0 + P1 + P2 + P3; \
    cs_ += __shfl_xor(cs_, 1); cs_ += __shfl_xor(cs_, 2); \
    cs_ += __shfl_xor(cs_, 4); cs_ += __shfl_xor(cs_, 8); \
    TM = tmax_; SM = cs_; }

    SMAX_E(0, m0_, s0_, p00, p10, p20, p30);
    SMAX_E(1, m1_, s1_, p01, p11, p21, p31);
    SMAX_E(2, m2_, s2_, p02, p12, p22, p32);
    SMAX_E(3, m3_, s3_, p03, p13, p23, p33);
#undef SMAX_E

    if (lrow == 0) {
        int rb = 16 * w + 4 * lkg;
        po[1280 + rb + 0] = m0_; po[1344 + rb + 0] = s0_;
        po[1280 + rb + 1] = m1_; po[1344 + rb + 1] = s1_;
        po[1280 + rb + 2] = m2_; po[1344 + rb + 2] = s2_;
        po[1280 + rb + 3] = m3_; po[1344 + rb + 3] = s3_;
    }
    __syncthreads();

#define PW(E, PJ0, PJ1, PJ2, PJ3) { \
    int r_ = (16 * w + 4 * lkg + E) * 72; \
    Pb[r_ + lrow]      = f2bf(PJ0); \
    Pb[r_ + 16 + lrow] = f2bf(PJ1); \
    Pb[r_ + 32 + lrow] = f2bf(PJ2); \
    Pb[r_ + 48 + lrow] = f2bf(PJ3); }
    PW(0, p00, p10, p20, p30);
    PW(1, p01, p11, p21, p31);
    PW(2, p02, p12, p22, p32);
    PW(3, p03, p13, p23, p33);
#undef PW
    __syncthreads();

    f32x4 O0 = {0,0,0,0}, O1 = {0,0,0,0}, O2 = {0,0,0,0};
#pragma unroll
    for (int ch = 0; ch < 2; ++ch) {
        short8v pf = *(const short8v*)&Pb[(16 * w + lrow) * 72 + ch * 32 + lkg * 8];
        short8v v0 = *(const short8v*)&Vb[(lrow) * 72 + ch * 32 + lkg * 8];
        short8v v1 = *(const short8v*)&Vb[(16 + lrow) * 72 + ch * 32 + lkg * 8];
        short8v v2 = *(const short8v*)&Vb[(32 + lrow) * 72 + ch * 32 + lkg * 8];
        O0 = __builtin_amdgcn_mfma_f32_16x16x32_bf16(pf, v0, O0, 0, 0, 0);
        O1 = __builtin_amdgcn_mfma_f32_16x16x32_bf16(pf, v1, O1, 0, 0, 0);
        O2 = __builtin_amdgcn_mfma_f32_16x16x32_bf16(pf, v2, O2, 0, 0, 0);
    }
#pragma unroll
    for (int e = 0; e < 4; ++e) {
        int r = 16 * w + 4 * lkg + e;
        poO[r * 40 + lrow]      = f2bf(O0[e]);
        poO[r * 40 + 16 + lrow] = f2bf(O1[e]);
        if (lrow < 8) poO[r * 40 + 32 + lrow] = f2bf(O2[e]);
    }
}

// ---------------- Kernel 3b: merge partials (r14, separate kernel) ----------------
__global__ __launch_bounds__(256) void attn_merge_kernel(
    const float* __restrict__ part,
    const float* __restrict__ rot, const float* __restrict__ trans,
    short* __restrict__ cat_bf)
{
    __shared__ float wsh[64 * 8];
    __shared__ float ob[64 * 44];

    const int bid = blockIdx.x;
    const int ic = bid % 6;
    const int h  = (bid / 6) % Hh;
    const int b  = bid / (6 * Hh);
    const int t  = threadIdx.x;
    const int i0 = ic * 64;
    const int bh = b * Hh + h;
    const size_t pbase = (((size_t)(bh * 6 + ic)) * 6) * PSTRIDE;

    if (t < 64) {
        float mk[6], sk[6];
        float M = -3.0e38f;
#pragma unroll
        for (int k = 0; k < 6; ++k) {
            mk[k] = part[pbase + (size_t)k * PSTRIDE + 1280 + t];
            sk[k] = part[pbase + (size_t)k * PSTRIDE + 1344 + t];
            M = fmaxf(M, mk[k]);
        }
        float wk[6]; float stot = 0.0f;
#pragma unroll
        for (int k = 0; k < 6; ++k) {
            wk[k] = __expf(mk[k] - M);
            stot += wk[k] * sk[k];
        }
        float inv = 1.0f / stot;
#pragma unroll
        for (int k = 0; k < 6; ++k) wsh[t * 8 + k] = wk[k] * inv;
    }
    __syncthreads();

#pragma unroll
    for (int it = 0; it < 10; ++it) {
        int idx = t + it * 256;
        int row = idx / 40, col = idx % 40;
        float v = 0.0f;
#pragma unroll
        for (int k = 0; k < 6; ++k) {
            const short* pO = (const short*)&part[pbase + (size_t)k * PSTRIDE];
            v += wsh[row * 8 + k] * bf2f(pO[row * 40 + col]);
        }
        ob[row * 44 + col] = v;
    }
    __syncthreads();

    {
        const int i = t >> 2;
        const int qq = t & 3;
        const int bnI = b * Nn + i0 + i;
        short* crow = cat_bf + (size_t)bnI * FCAT;

        float4 o = *(const float4*)&ob[i * 44 + 4 * qq];
        crow[h * 16 + 4 * qq + 0] = f2bf(o.x);
        crow[h * 16 + 4 * qq + 1] = f2bf(o.y);
        crow[h * 16 + 4 * qq + 2] = f2bf(o.z);
        crow[h * 16 + 4 * qq + 3] = f2bf(o.w);

        const float* R = rot + (size_t)bnI * 9;
        const float* T = trans + (size_t)bnI * 3;
#pragma unroll
        for (int e = 0; e < 2; ++e) {
            int pe = qq + 4 * e;
            float g0 = ob[i * 44 + 16 + 3 * pe + 0] - T[0];
            float g1 = ob[i * 44 + 16 + 3 * pe + 1] - T[1];
            float g2 = ob[i * 44 + 16 + 3 * pe + 2] - T[2];
            float lx = R[0]*g0 + R[3]*g1 + R[6]*g2;
            float ly = R[1]*g0 + R[4]*g1 + R[7]*g2;
            float lz = R[2]*g0 + R[5]*g1 + R[8]*g2;
            crow[192 + h * 8 + pe] = f2bf(lx);
            crow[288 + h * 8 + pe] = f2bf(ly);
            crow[384 + h * 8 + pe] = f2bf(lz);
            crow[480 + h * 8 + pe] = f2bf(sqrtf(lx*lx + ly*ly + lz*lz + EPSV));
        }
    }
}

// ---------------- Kernel 4: output GEMM via bf16 MFMA (in-kernel w_out conversion) ----------------
__global__ __launch_bounds__(256) void out_kernel(
    const short* __restrict__ cat_bf, const float* __restrict__ w_out,
    const float* __restrict__ b_out, float* __restrict__ out)
{
    __shared__ short Al[32 * 40];
    __shared__ short Bl[64 * 40];

    const int bm = blockIdx.x % 48;
    const int bn = blockIdx.x / 48;
    const int m0 = bm * 32;
    const int n0 = bn * 64;
    const int t = threadIdx.x;
    const int w = t >> 6;
    const int lane = t & 63;
    const int lrow = lane & 15;
    const int lkg  = lane >> 4;
    const int r0 = 16 * (w & 1);
    const int c0 = 32 * (w >> 1);
    const int nl  = t & 63;
    const int kk8 = t >> 6;

    f32x4 acc0 = {0,0,0,0}, acc1 = {0,0,0,0};

    for (int ks = 0; ks < 18; ++ks) {
        const int kbase = ks * 32;
        if (t < 128) {
            int arow = t >> 2, aseg = t & 3;
            *(short8v*)&Al[arow * 40 + aseg * 8] =
                *(const short8v*)&cat_bf[(size_t)(m0 + arow) * FCAT + kbase + aseg * 8];
        }
        {
            const float* wp = w_out + (size_t)(kbase + kk8 * 8) * 384 + n0 + nl;
            short8v bv;
#pragma unroll
            for (int j = 0; j < 8; ++j) bv[j] = f2bf(wp[(size_t)j * 384]);
            *(short8v*)&Bl[nl * 40 + kk8 * 8] = bv;
        }
        __syncthreads();

        short8v av = *(const short8v*)&Al[(r0 + lrow) * 40 + lkg * 8];
        short8v b0 = *(const short8v*)&Bl[(c0 + lrow) * 40 + lkg * 8];
        short8v b1 = *(const short8v*)&Bl[(c0 + 16 + lrow) * 40 + lkg * 8];
        acc0 = __builtin_amdgcn_mfma_f32_16x16x32_bf16(av, b0, acc0, 0, 0, 0);
        acc1 = __builtin_amdgcn_mfma_f32_16x16x32_bf16(av, b1, acc1, 0, 0, 0);
        __syncthreads();
    }

    const int orow = m0 + r0 + lkg * 4;
#pragma unroll
    for (int e = 0; e < 4; ++e) {
        float* pr = out + (size_t)(orow + e) * 384 + n0 + c0;
        pr[lrow]      = acc0[e] + b_out[n0 + c0 + lrow];
        pr[16 + lrow] = acc1[e] + b_out[n0 + c0 + 16 + lrow];
    }
}

extern "C" void kernel_launch(void* const* d_in, const int* in_sizes, int n_in,
                              void* d_out, int out_size, void* d_ws, size_t ws_size,
                              hipStream_t stream) {
    const float* s     = (const float*)d_in[0];
    const float* rot   = (const float*)d_in[2];
    const float* trans = (const float*)d_in[3];
    const float* mask  = (const float*)d_in[4];
    const float* w_q   = (const float*)d_in[5];
    const float* b_q   = (const float*)d_in[6];
    const float* w_kv  = (const float*)d_in[7];
    const float* b_kv  = (const float*)d_in[8];
    const float* w_qp  = (const float*)d_in[13];
    const float* b_qp  = (const float*)d_in[14];
    const float* w_kvp = (const float*)d_in[15];
    const float* b_kvp = (const float*)d_in[16];
    const float* hwts  = (const float*)d_in[17];
    const float* w_out = (const float*)d_in[18];
    const float* b_out = (const float*)d_in[19];

    float* ws     = (float*)d_ws;
    float* proj   = ws + WS_PROJ;
    short* cat_bf = (short*)(ws + WS_CAT);
    float* partb  = ws + WS_PART;
    short* Ah     = (short*)(ws + WS_AH);
    short* Alp    = (short*)(ws + WS_AL);
    short* Kh     = (short*)(ws + WS_KH);
    short* Kl     = (short*)(ws + WS_KL);
    short* Vbp    = (short*)(ws + WS_VBP);
    float* out    = (float*)d_out;

    hipLaunchKernelGGL(proj_kernel, dim3(432), dim3(256), 0, stream,
                       s, w_q, w_kv, w_qp, w_kvp, b_q, b_kv, b_qp, b_kvp, proj);
    hipLaunchKernelGGL(pack_kernel, dim3(1536), dim3(192), 0, stream,
                       proj, rot, trans, hwts, mask, Ah, Alp, Kh, Kl, Vbp);
    hipLaunchKernelGGL(attn_part_kernel, dim3(1728), dim3(256), 0, stream,
                       Ah, Alp, Kh, Kl, Vbp, partb);
    hipLaunchKernelGGL(attn_merge_kernel, dim3(288), dim3(256), 0, stream,
                       partb, rot, trans, cat_bf);
    hipLaunchKernelGGL(out_kernel, dim3(288), dim3(256), 0, stream,
                       cat_bf, w_out, b_out, out);
}